// Round 2
// baseline (2982.584 us; speedup 1.0000x reference)
//
#include <hip/hip_runtime.h>
#include <hip/hip_bf16.h>

typedef unsigned short u16;
typedef unsigned int u32;

// ---------------- LayerNorm (f32 in) : writes h (f32) and optionally acc = x ----
__global__ __launch_bounds__(256) void k_ln(const float* __restrict__ x, const float* __restrict__ g,
    const float* __restrict__ b, float* __restrict__ hout, float* __restrict__ acc) {
  int token = blockIdx.x * 4 + (threadIdx.x >> 6);
  int lane = threadIdx.x & 63;
  long base = (long)token * 64 + lane;
  float v = x[base];
  float s = v;
#pragma unroll
  for (int o = 32; o; o >>= 1) s += __shfl_xor(s, o);
  float m = s * 0.015625f;
  float d = v - m;
  float q = d * d;
#pragma unroll
  for (int o = 32; o; o >>= 1) q += __shfl_xor(q, o);
  float r = rsqrtf(q * 0.015625f + 1e-5f);
  hout[base] = d * r * g[lane] + b[lane];
  if (acc) acc[base] = v;
}

// ---------------- Spatial window attention: one block per (window, head) --------
// windows: (b, d0<4, h0<16, w0<16), tokens n = dz*49+hy*7+wx (98), head dim 16
__global__ __launch_bounds__(256) void k_sattn(const float* __restrict__ h, const float* __restrict__ qw,
    const float* __restrict__ qb, const float* __restrict__ rpb, float* __restrict__ aout) {
  __shared__ __align__(16) float smem[14308];
  float* sS = smem;          // 9604 scores; first 6272 double as x-window
  float* sQ = smem + 9604;   // 1568 = 98*16
  float* sK = sQ + 1568;
  float* sV = sK + 1568;
  int tid = threadIdx.x;
  int blk = blockIdx.x;
  int hd = blk & 3;
  int wi = blk >> 2;
  int b = wi >> 10, d0 = (wi >> 8) & 3, h0 = (wi >> 4) & 15, w0 = wi & 15;

  // phase 0: load window tokens (98 x 64)
  for (int i = tid; i < 6272; i += 256) {
    int n = i >> 6, c = i & 63;
    int dz = n / 49, r = n - dz * 49, hy = r / 7, wx = r - hy * 7;
    long p = ((long)(b * 8 + d0 * 2 + dz) * 112 + (h0 * 7 + hy)) * 112 + (w0 * 7 + wx);
    sS[i] = h[p * 64 + c];
  }
  __syncthreads();
  // phase 1: qkv for this head's 48 columns (16 per part)
  for (int i = tid; i < 1176; i += 256) {
    int part = i / 392;
    int rr = i - part * 392;
    int n = rr >> 2, j4 = (rr & 3) << 2;
    int colbase = part * 64 + hd * 16 + j4;
    float4 a4 = *(const float4*)(qb + colbase);
    float a0 = a4.x, a1 = a4.y, a2 = a4.z, a3 = a4.w;
    const float* xr = &sS[n << 6];
    const float* wp = qw + colbase;
    for (int c = 0; c < 64; c++) {
      float xv = xr[c];
      float4 w4 = *(const float4*)(wp + c * 192);
      a0 += xv * w4.x;
      a1 += xv * w4.y;
      a2 += xv * w4.z;
      a3 += xv * w4.w;
    }
    float* dst = part == 0 ? sQ : (part == 1 ? sK : sV);
    float sc = part == 0 ? 0.25f : 1.0f;
    int o = n * 16 + j4;
    dst[o] = a0 * sc; dst[o + 1] = a1 * sc; dst[o + 2] = a2 * sc; dst[o + 3] = a3 * sc;
  }
  __syncthreads();
  // phase 2: scores + relative position bias
  for (int i = tid; i < 2450; i += 256) {
    int n = i / 25, mc = i - n * 25;
    int m0 = mc * 4;
    float4 q0 = *(float4*)&sQ[n * 16], q1 = *(float4*)&sQ[n * 16 + 4];
    float4 q2 = *(float4*)&sQ[n * 16 + 8], q3 = *(float4*)&sQ[n * 16 + 12];
    int dzn = n / 49, rn = n - dzn * 49, hyn = rn / 7, wxn = rn - hyn * 7;
    int mend = (m0 + 4 > 98) ? 98 : m0 + 4;
    for (int m = m0; m < mend; m++) {
      float4 k0 = *(float4*)&sK[m * 16], k1 = *(float4*)&sK[m * 16 + 4];
      float4 k2 = *(float4*)&sK[m * 16 + 8], k3 = *(float4*)&sK[m * 16 + 12];
      float sv = q0.x * k0.x + q0.y * k0.y + q0.z * k0.z + q0.w * k0.w
               + q1.x * k1.x + q1.y * k1.y + q1.z * k1.z + q1.w * k1.w
               + q2.x * k2.x + q2.y * k2.y + q2.z * k2.z + q2.w * k2.w
               + q3.x * k3.x + q3.y * k3.y + q3.z * k3.z + q3.w * k3.w;
      int dzm = m / 49, rm = m - dzm * 49, hym = rm / 7, wxm = rm - hym * 7;
      int idx = (dzn - dzm + 1) * 169 + (hyn - hym + 6) * 13 + (wxn - wxm + 6);
      sS[n * 98 + m] = sv + rpb[idx * 4 + hd];
    }
  }
  __syncthreads();
  // phase 3: softmax per row
  if (tid < 98) {
    float* row = &sS[tid * 98];
    float mx = -1e30f;
    for (int m = 0; m < 98; m++) mx = fmaxf(mx, row[m]);
    float sum = 0.f;
    for (int m = 0; m < 98; m++) { float e = __expf(row[m] - mx); row[m] = e; sum += e; }
    float inv = 1.f / sum;
    for (int m = 0; m < 98; m++) row[m] *= inv;
  }
  __syncthreads();
  // phase 4: P @ V -> attn out (pre-projection), layout (window, n, 64)
  for (int i = tid; i < 392; i += 256) {
    int n = i >> 2, e0 = (i & 3) << 2;
    float a0 = 0, a1 = 0, a2 = 0, a3 = 0;
    const float* prow = &sS[n * 98];
    for (int m = 0; m < 98; m++) {
      float p = prow[m];
      float4 vv = *(float4*)&sV[m * 16 + e0];
      a0 += p * vv.x; a1 += p * vv.y; a2 += p * vv.z; a3 += p * vv.w;
    }
    long ob = ((long)wi * 98 + n) * 64 + hd * 16 + e0;
    aout[ob] = a0; aout[ob + 1] = a1; aout[ob + 2] = a2; aout[ob + 3] = a3;
  }
}

// ---------------- Spatial projection: (nw*98,64)@(64,64) scatter-add into acc ---
__global__ __launch_bounds__(256) void k_sproj(const float* __restrict__ ain, const float* __restrict__ pw,
    const float* __restrict__ pb, float* __restrict__ acc) {
  __shared__ float srow[4][64];
  int wv = threadIdx.x >> 6, c = threadIdx.x & 63;
  int row = blockIdx.x * 4 + wv;
  srow[wv][c] = ain[(long)row * 64 + c];
  __syncthreads();
  float a = pb[c];
  const float* xr = srow[wv];
  const float* wp = pw + c;
  for (int k = 0; k < 64; k++) a += xr[k] * wp[k * 64];
  int wi = row / 98, n = row - wi * 98;
  int b = wi >> 10, d0 = (wi >> 8) & 3, h0 = (wi >> 4) & 15, w0 = wi & 15;
  int dz = n / 49, r2 = n - dz * 49, hy = r2 / 7, wx = r2 - hy * 7;
  long p = ((long)(b * 8 + d0 * 2 + dz) * 112 + (h0 * 7 + hy)) * 112 + (w0 * 7 + wx);
  acc[p * 64 + c] += a;
}

// ---------------- Temporal attention: one wave per pixel sequence (D=8) ---------
__global__ __launch_bounds__(256) void k_tattn(const float* __restrict__ h, const float* __restrict__ qw,
    const float* __restrict__ qb, const float* __restrict__ rpbt, const float* __restrict__ pw,
    const float* __restrict__ pb, float* __restrict__ acc) {
  __shared__ float sm[4][1600];
  int wv = threadIdx.x >> 6, lane = threadIdx.x & 63;
  int s = blockIdx.x * 4 + wv;
  int b = s / 12544, rr = s - b * 12544, hy = rr / 112, wx = rr - hy * 112;
  float* xt = sm[wv];       // 512
  float* qkv = xt + 512;    // 768
  float* sp = qkv + 768;    // 64
  float* o = sp + 64;       // 256
  long pbase = ((long)b * 896 + hy) * 112 + wx;   // pos of token n = pbase + n*12544
  for (int i = lane; i < 512; i += 64) {
    int n = i >> 6, c = i & 63;
    xt[i] = h[(pbase + (long)n * 12544) * 64 + c];
  }
  __syncthreads();
  // qkv (8 x 96)
  for (int i = lane; i < 192; i += 64) {
    int n = i / 24, c4 = (i - n * 24) * 4;
    float4 a4 = *(const float4*)(qb + c4);
    float a0 = a4.x, a1 = a4.y, a2 = a4.z, a3 = a4.w;
    const float* xr = &xt[n * 64];
    const float* wp = qw + c4;
    for (int c = 0; c < 64; c++) {
      float xv = xr[c];
      float4 w4 = *(const float4*)(wp + c * 96);
      a0 += xv * w4.x; a1 += xv * w4.y;
      a2 += xv * w4.z; a3 += xv * w4.w;
    }
    float sc = (c4 < 32) ? 0.25f : 1.f;
    int ob = n * 96 + c4;
    qkv[ob] = a0 * sc; qkv[ob + 1] = a1 * sc; qkv[ob + 2] = a2 * sc; qkv[ob + 3] = a3 * sc;
  }
  __syncthreads();
  int n8 = lane >> 3, m8 = lane & 7;
  for (int hd = 0; hd < 4; hd++) {
    float sc = 0.f;
    const float* qr = &qkv[n8 * 96 + hd * 8];
    const float* kr = &qkv[m8 * 96 + 32 + hd * 8];
#pragma unroll
    for (int e = 0; e < 8; e++) sc += qr[e] * kr[e];
    sc += rpbt[(n8 - m8 + 7) * 4 + hd];
    sp[lane] = sc;
    __syncthreads();
    if (lane < 8) {
      float* row = &sp[lane * 8];
      float mx = -1e30f;
      for (int m = 0; m < 8; m++) mx = fmaxf(mx, row[m]);
      float sum = 0.f;
      for (int m = 0; m < 8; m++) { float e = __expf(row[m] - mx); row[m] = e; sum += e; }
      float inv = 1.f / sum;
      for (int m = 0; m < 8; m++) row[m] *= inv;
    }
    __syncthreads();
    float a = 0.f;
    const float* prow = &sp[n8 * 8];
#pragma unroll
    for (int m = 0; m < 8; m++) a += prow[m] * qkv[m * 96 + 64 + hd * 8 + m8];
    o[n8 * 32 + hd * 8 + m8] = a;
    __syncthreads();
  }
  // projection (32 -> 64), add into acc
  for (int i = lane; i < 128; i += 64) {
    int n = i >> 4, c4 = (i & 15) << 2;
    float4 a4 = *(const float4*)(pb + c4);
    float a0 = a4.x, a1 = a4.y, a2 = a4.z, a3 = a4.w;
    const float* orow = &o[n * 32];
    const float* wp = pw + c4;
    for (int k = 0; k < 32; k++) {
      float ov = orow[k];
      float4 w4 = *(const float4*)(wp + k * 64);
      a0 += ov * w4.x; a1 += ov * w4.y; a2 += ov * w4.z; a3 += ov * w4.w;
    }
    long ab = (pbase + (long)n * 12544) * 64 + c4;
    acc[ab] += a0; acc[ab + 1] += a1; acc[ab + 2] += a2; acc[ab + 3] += a3;
  }
}

// ---------------- Direct 3x3x3 conv, channels-last, 32ci -> 32co ----------------
// grid (2, 112, 16=b*8+d); block 256 = 8 w-groups x 32 co; each thread 8 outputs
__global__ __launch_bounds__(256) void k_conv(const float* __restrict__ in, int ics,
    const float* __restrict__ wgt, const float* __restrict__ bias,
    const float* __restrict__ addsrc, int acs, float* __restrict__ out, int lrelu) {
  __shared__ __align__(16) float s_in[32 * 68];
  __shared__ float s_w[32 * 97];
  int tid = threadIdx.x;
  int co = tid & 31, ws8 = tid >> 5;
  int wtile = blockIdx.x, hh = blockIdx.y, bz = blockIdx.z;
  int d = bz & 7, bb = bz >> 3;
  int wbase = wtile * 64;
  float acc[8];
#pragma unroll
  for (int q = 0; q < 8; q++) acc[q] = 0.f;
  for (int kd = 0; kd < 3; kd++) {
    int zd = d + kd - 1;
    if (zd < 0 || zd > 7) continue;
    for (int kh = 0; kh < 3; kh++) {
      int yy = hh + kh - 1;
      if (yy < 0 || yy > 111) continue;
      __syncthreads();
      int prow = ((bb * 8 + zd) * 112 + yy) * 112;
      for (int i = tid; i < 2112; i += 256) {
        int ci = i & 31, j = i >> 5;
        int w = wbase - 1 + j;
        float v = 0.f;
        if (w >= 0 && w < 112) v = in[(long)(prow + w) * ics + ci];
        s_in[ci * 68 + j] = v;
      }
      for (int i = tid; i < 3072; i += 256) {
        int c2 = i / 96, r = i - c2 * 96;
        int ci = r / 3, kw = r - ci * 3;
        s_w[c2 * 97 + r] = wgt[(c2 * 32 + ci) * 27 + kd * 9 + kh * 3 + kw];
      }
      __syncthreads();
      int jb = ws8 * 8;
      for (int ci = 0; ci < 32; ci++) {
        const float* ip = &s_in[ci * 68 + jb];
        float4 A = *(const float4*)ip;
        float4 Bv = *(const float4*)(ip + 4);
        float2 Cv = *(const float2*)(ip + 8);
        float v[10] = {A.x, A.y, A.z, A.w, Bv.x, Bv.y, Bv.z, Bv.w, Cv.x, Cv.y};
        const float* wr = &s_w[co * 97 + ci * 3];
        float w0 = wr[0], w1 = wr[1], w2 = wr[2];
#pragma unroll
        for (int q = 0; q < 8; q++)
          acc[q] += v[q] * w0 + v[q + 1] * w1 + v[q + 2] * w2;
      }
    }
  }
  float bv = bias[co];
  int w00 = wbase + ws8 * 8;
  int pcol = (bz * 112 + hh) * 112;
#pragma unroll
  for (int q = 0; q < 8; q++) {
    int w = w00 + q;
    if (w < 112) {
      float vv = acc[q] + bv;
      if (lrelu) vv = vv > 0.f ? vv : 0.01f * vv;
      long pos = pcol + w;
      if (addsrc) vv += addsrc[pos * acs + co];
      out[pos * 32 + co] = vv;
    }
  }
}

// ---------------- x2 += y1 (in place in h2's channel 32..63) --------------------
__global__ __launch_bounds__(256) void k_addx2(float* __restrict__ h2, const float* __restrict__ y1) {
  long i = (long)blockIdx.x * 256 + threadIdx.x;
  long pos = i >> 5;
  int c = (int)(i & 31);
  h2[pos * 64 + 32 + c] += y1[i];
}

// ---------------- out = acc + concat(y1,y2) -------------------------------------
__global__ __launch_bounds__(256) void k_final(const float* __restrict__ acc, const float* __restrict__ y1,
    const float* __restrict__ y2, float* __restrict__ out) {
  long i = (long)blockIdx.x * 256 + threadIdx.x;
  long pos = i >> 6;
  int c = (int)(i & 63);
  float v = acc[i] + (c < 32 ? y1[pos * 32 + c] : y2[pos * 32 + c - 32]);
  out[i] = v;
}

extern "C" void kernel_launch(void* const* d_in, const int* in_sizes, int n_in,
                              void* d_out, int out_size, void* d_ws, size_t ws_size,
                              hipStream_t stream) {
  const float* x        = (const float*)d_in[0];
  // d_in[1] mask_matrix: unused (all zeros in reference path)
  const float* g1       = (const float*)d_in[2];
  const float* b1       = (const float*)d_in[3];
  const float* rpb_s    = (const float*)d_in[4];
  const float* qkv_w_s  = (const float*)d_in[5];
  const float* qkv_b_s  = (const float*)d_in[6];
  const float* proj_w_s = (const float*)d_in[7];
  const float* proj_b_s = (const float*)d_in[8];
  const float* rpb_t    = (const float*)d_in[9];
  const float* qkv_w_t  = (const float*)d_in[10];
  const float* qkv_b_t  = (const float*)d_in[11];
  const float* proj_w_t = (const float*)d_in[12];
  const float* proj_b_t = (const float*)d_in[13];
  const float* g2       = (const float*)d_in[14];
  const float* b2       = (const float*)d_in[15];
  const float* c1w = (const float*)d_in[16];
  const float* c1b = (const float*)d_in[17];
  const float* c2w = (const float*)d_in[18];
  const float* c2b = (const float*)d_in[19];
  const float* c3w = (const float*)d_in[20];
  const float* c3b = (const float*)d_in[21];
  const float* c4w = (const float*)d_in[22];
  const float* c4b = (const float*)d_in[23];

  // workspace layout (fp32): acc | hbuf(h/h2) | tbuf | y1 | y2  = ~180 MB
  float* acc  = (float*)d_ws;
  float* hbuf = acc + 12845056;
  float* tbuf = hbuf + 12845056;
  float* y1   = tbuf + 6422528;
  float* y2   = y1 + 6422528;
  float* aout = tbuf;  // spans tbuf..y1 (12.85M floats), dead before convs start

  // 1. LN1: h = LN(x); acc = x
  k_ln<<<50176, 256, 0, stream>>>(x, g1, b1, hbuf, acc);
  // 2. spatial window attention (qkv + softmax + PV) -> aout
  k_sattn<<<8192, 256, 0, stream>>>(hbuf, qkv_w_s, qkv_b_s, rpb_s, aout);
  // 3. spatial projection, scatter-add into acc
  k_sproj<<<50176, 256, 0, stream>>>(aout, proj_w_s, proj_b_s, acc);
  // 4. temporal attention, add into acc
  k_tattn<<<6272, 256, 0, stream>>>(hbuf, qkv_w_t, qkv_b_t, rpb_t, proj_w_t, proj_b_t, acc);
  // 5. LN2: h2 = LN(acc)   (channels-last kept; reference transpose is layout-only)
  k_ln<<<50176, 256, 0, stream>>>(acc, g2, b2, hbuf, nullptr);
  // 6. conv path 1: t = lrelu(conv(x1)); y1 = x1 + conv(t)
  k_conv<<<dim3(2, 112, 16), 256, 0, stream>>>(hbuf, 64, c1w, c1b, nullptr, 0, tbuf, 1);
  k_conv<<<dim3(2, 112, 16), 256, 0, stream>>>(tbuf, 32, c2w, c2b, hbuf, 64, y1, 0);
  // 7. x2 += y1 (in place)
  k_addx2<<<25088, 256, 0, stream>>>(hbuf, y1);
  // 8. conv path 2: t = lrelu(conv(x2b)); y2 = x2b + conv(t)
  k_conv<<<dim3(2, 112, 16), 256, 0, stream>>>(hbuf + 32, 64, c3w, c3b, nullptr, 0, tbuf, 1);
  k_conv<<<dim3(2, 112, 16), 256, 0, stream>>>(tbuf, 32, c4w, c4b, hbuf + 32, 64, y2, 0);
  // 9. out = acc + concat(y1, y2)
  k_final<<<50176, 256, 0, stream>>>(acc, y1, y2, (float*)d_out);
}